// Round 13
// baseline (151.476 us; speedup 1.0000x reference)
//
#include <hip/hip_runtime.h>
#include <hip/hip_bf16.h>
#include <math.h>

#define CDIM 192
#define NHEADS 6
#define WIN 7
#define KWIN 49
#define BATCH 4
#define PIX 3136      // 56*56
#define NPIX 12544    // BATCH*PIX
#define NIMG 24       // BATCH*NHEADS
#define EPSV 1e-5f

typedef __bf16 bf16x8 __attribute__((ext_vector_type(8)));
typedef float f32x16 __attribute__((ext_vector_type(16)));
typedef unsigned int uint4v __attribute__((ext_vector_type(4)));
typedef unsigned int uint2v __attribute__((ext_vector_type(2)));
typedef unsigned short u16;
typedef unsigned char u8;

__device__ inline u8 f32_to_fp8(float v) {
  return (u8)(__builtin_amdgcn_cvt_pk_fp8_f32(v, 0.f, 0, false) & 0xFF);
}

// ---------------- BN stats ---------------------------------------------------
__global__ __launch_bounds__(256) void bn_stats_k(const float* __restrict__ x,
                                                  float* __restrict__ stats) {
  int c = blockIdx.x;
  float s = 0.f, q = 0.f;
  for (int n = threadIdx.x; n < BATCH * PIX; n += 256) {
    int b = n / PIX, p = n - b * PIX;
    float v = x[((size_t)b * CDIM + c) * PIX + p];
    s += v; q += v * v;
  }
  __shared__ float rs[256], rq[256];
  rs[threadIdx.x] = s; rq[threadIdx.x] = q;
  __syncthreads();
  for (int st = 128; st > 0; st >>= 1) {
    if (threadIdx.x < st) { rs[threadIdx.x] += rs[threadIdx.x + st]; rq[threadIdx.x] += rq[threadIdx.x + st]; }
    __syncthreads();
  }
  if (threadIdx.x == 0) {
    float mean = rs[0] / (float)(BATCH * PIX);
    float var = rq[0] / (float)(BATCH * PIX) - mean * mean;
    stats[c] = mean;
    stats[CDIM + c] = rsqrtf(var + EPSV);
  }
}

// ------- fold BN + q-scale into qkv weights, writing PACKED frags directly --
__global__ __launch_bounds__(192) void fold_pack_k(
    const float* __restrict__ qkv_w, const float* __restrict__ qkv_b,
    const float* __restrict__ gamma, const float* __restrict__ beta,
    const float* __restrict__ stats, u16* __restrict__ pk_qkv,
    float* __restrict__ b_eff) {
  int o = blockIdx.x, c = threadIdx.x;
  float alpha = gamma[c] * stats[CDIM + c];
  float shift = beta[c] - stats[c] * alpha;
  float w = qkv_w[o * CDIM + c];
  float scale = (o < CDIM) ? 0.17677669529663687f : 1.f;
  int t8 = ((((o >> 5) * 12 + (c >> 4)) * 64 + (((c >> 3) & 1) * 32 + (o & 31))) << 3) + (c & 7);
  ((__hip_bfloat16*)pk_qkv)[t8] = __float2bfloat16(w * alpha * scale);
  __shared__ float r[CDIM];
  r[c] = w * shift;
  __syncthreads();
  if (c == 0) {
    float s = 0.f;
    for (int i = 0; i < CDIM; i++) s += r[i];
    b_eff[o] = (qkv_b[o] + s) * scale;
  }
}

// ---------------- generic pack helper: W[Cout][Cin] -> frag-major -----------
__device__ inline void pack_one(const float* __restrict__ W, u16* __restrict__ out,
                                int Cin, int t) {
  int lane = t & 63, rest = t >> 6;
  int nK = Cin >> 4;
  int kk = rest % nK, mtg = rest / nK;
  int o = mtg * 32 + (lane & 31), c = kk * 16 + (lane >> 5) * 8;
  const float* src = W + (size_t)o * Cin + c;
  __hip_bfloat16 tmp[8];
#pragma unroll
  for (int e = 0; e < 8; e++) tmp[e] = __float2bfloat16(src[e]);
  *(uint4v*)(out + (size_t)t * 8) = *(uint4v*)tmp;
}

// --- merged prep: dm_w FP8 pack + proj/c1/c2 packs --------------------------
__global__ __launch_bounds__(256) void prep3_k(
    const float* __restrict__ dm_w, u8* __restrict__ wTb8,
    const float* __restrict__ proj_w, u16* __restrict__ pk_proj,
    const float* __restrict__ c1_w, u16* __restrict__ pk_c1,
    const float* __restrict__ c2_w, u16* __restrict__ pk_c2) {
  int bid = blockIdx.x, tid = threadIdx.x;
  if (bid < 784) {
    int idx = bid * 256 + tid;
    int e = idx & 7;
    int tmp = idx >> 3;
    int lane = tmp & 63; tmp >>= 6;
    int ch = tmp & 3; tmp >>= 2;
    int tap = tmp % 49, Mt = tmp / 49;
    int ko = Mt * 32 + (lane & 31);
    int ci = ch * 16 + (lane >> 5) * 8 + e;
    float v = (ko < KWIN) ? dm_w[(size_t)ko * 3136 + ci * 49 + tap] : 0.f;
    wTb8[idx] = f32_to_fp8(v);
  } else if (bid < 802) {
    int t = (bid - 784) * 256 + tid;
    if (t < 4608) pack_one(proj_w, pk_proj, 192, t);
  } else if (bid < 874) {
    int t = (bid - 802) * 256 + tid;
    if (t < 18432) pack_one(c1_w, pk_c1, 192, t);
  } else {
    int t = (bid - 874) * 256 + tid;
    if (t < 18432) pack_one(c2_w, pk_c2, 768, t);
  }
}

// ---------------- MFMA GEMM (256px tile + A staged in LDS) ------------------
// MT = number of 32-o M-tiles per block (2 -> 64 o, 1 -> 32 o for small grids).
#define MG_QKV 0
#define MG_PROJ 1
#define MG_GELU 2
#define MG_C2 3
#define MGS 2056

template <int EPI, int MT>
__global__ __launch_bounds__(256, 3) void mgemm_k(
    const u16* __restrict__ Bm, const u16* __restrict__ Apk,
    const float* __restrict__ bias,
    float* __restrict__ outF, u16* __restrict__ outT, u16* __restrict__ outT2,
    const float* __restrict__ extra, int Cin) {
  __shared__ __align__(16) u16 Bs[8 * MGS];  // 32.9 KB
  __shared__ __align__(16) u16 As[4096];     // 8 KB
  int tid = threadIdx.x;
  int lane = tid & 63, wid = tid >> 6;
  int hi = lane >> 5, ln31 = lane & 31;
  int p0 = blockIdx.x * 256;
  int o0 = blockIdx.y * (32 * MT);
  int nK = Cin >> 4;
  f32x16 acc[MT][2];
#pragma unroll
  for (int mt = 0; mt < MT; mt++)
#pragma unroll
    for (int nt = 0; nt < 2; nt++)
#pragma unroll
      for (int i = 0; i < 16; i++) acc[mt][nt][i] = 0.f;

  // for QKV direct-x staging
  unsigned gp_s = p0 + tid;
  unsigned bb_s = gp_s / PIX, pp_s = gp_s - bb_s * PIX;

  for (int cc = 0; cc < Cin; cc += 64) {
    if (EPI == MG_QKV) {
#pragma unroll
      for (int g = 0; g < 8; g++) {
        const float* xb = extra + ((size_t)bb_s * CDIM + cc + g * 8) * PIX + pp_s;
        __hip_bfloat16 tmp[8];
#pragma unroll
        for (int e = 0; e < 8; e++) tmp[e] = __float2bfloat16(xb[(size_t)e * PIX]);
        *(uint4v*)&Bs[g * MGS + tid * 8] = *(uint4v*)tmp;
      }
    } else {
#pragma unroll
      for (int i = 0; i < 8; i++) {
        int idx = i * 256 + tid;
        int g = idx & 7, p = idx >> 3;
        uint4v v = *(const uint4v*)(Bm + (size_t)(p0 + p) * Cin + cc + g * 8);
        *(uint4v*)&Bs[g * MGS + p * 8] = v;
      }
    }
#pragma unroll
    for (int i = 0; i < MT; i++) {
      int idx = i * 256 + tid;
      int frag = idx >> 6, l64 = idx & 63;
      int mt = frag >> 2, ks = frag & 3;
      uint4v v = *(const uint4v*)(Apk +
          (size_t)(((o0 >> 5) + mt) * nK + (cc >> 4) + ks) * 512 + l64 * 8);
      *(uint4v*)&As[frag * 512 + l64 * 8] = v;
    }
    __syncthreads();
    int pA = wid * 64 + ln31;
    int pB = pA + 32;
#pragma unroll
    for (int ks = 0; ks < 4; ks++) {
      int g = ks * 2 + hi;
      bf16x8 b0 = *(const bf16x8*)&Bs[g * MGS + pA * 8];
      bf16x8 b1 = *(const bf16x8*)&Bs[g * MGS + pB * 8];
#pragma unroll
      for (int mt = 0; mt < MT; mt++) {
        bf16x8 a = *(const bf16x8*)&As[(mt * 4 + ks) * 512 + lane * 8];
        acc[mt][0] = __builtin_amdgcn_mfma_f32_32x32x16_bf16(a, b0, acc[mt][0], 0, 0, 0);
        acc[mt][1] = __builtin_amdgcn_mfma_f32_32x32x16_bf16(a, b1, acc[mt][1], 0, 0, 0);
      }
    }
    __syncthreads();
  }

  // ---- epilogue ----
  if (EPI == MG_C2) {
#pragma unroll
    for (int mt = 0; mt < MT; mt++)
#pragma unroll
      for (int r = 0; r < 16; r++) {
        int o = o0 + mt * 32 + (r & 3) + 8 * (r >> 2) + 4 * hi;
        float bv = bias[o];
#pragma unroll
        for (int nt = 0; nt < 2; nt++) {
          unsigned gp = p0 + wid * 64 + nt * 32 + ln31;
          unsigned bb = gp / PIX, pp = gp - bb * PIX;
          size_t oi = ((size_t)bb * CDIM + o) * PIX + pp;
          outF[oi] = acc[mt][nt][r] + bv + extra[oi];
        }
      }
  } else {
#pragma unroll
    for (int mt = 0; mt < MT; mt++)
#pragma unroll
      for (int r = 0; r < 16; r++) {
        int o_loc = mt * 32 + (r & 3) + 8 * (r >> 2) + 4 * hi;
        int o = o0 + o_loc;
        float bv = bias[o];
#pragma unroll
        for (int nt = 0; nt < 2; nt++) {
          int p_loc = wid * 64 + nt * 32 + ln31;
          float val = acc[mt][nt][r] + bv;
          if (EPI == MG_PROJ) {
            unsigned gp = p0 + p_loc;
            unsigned bb = gp / PIX, pp = gp - bb * PIX;
            size_t oi = ((size_t)bb * CDIM + o) * PIX + pp;
            val += extra[oi];
            outF[oi] = val;
          }
          if (EPI == MG_GELU)
            val = 0.5f * val * (1.f + erff(val * 0.70710678118654752f));
          *(__hip_bfloat16*)&Bs[p_loc * 64 + (((o_loc >> 3) ^ (p_loc & 7)) << 3) + (o_loc & 7)] =
              __float2bfloat16(val);
        }
      }
    __syncthreads();
    int prow = wid * 64 + lane;
    int psw = prow & 7;
    uint4v r8[4 * MT];
#pragma unroll
    for (int g = 0; g < 4 * MT; g++)
      r8[g] = *(const uint4v*)&Bs[prow * 64 + ((g ^ psw) << 3)];
    unsigned gp = p0 + prow;
    if (EPI == MG_QKV) {
      unsigned bb = gp / PIX, pp = gp - bb * PIX;
      int s = o0 / 192;               // 0=q, 1=k, 2=v
      int rr = o0 - s * 192;
      int h0 = rr >> 5;
      if (s < 2) {
        u16* d0 = outT + ((size_t)(bb * NHEADS + h0) * PIX + pp) * 64 + s * 32;
        u16* d1 = outT + ((size_t)(bb * NHEADS + h0 + 1) * PIX + pp) * 64 + s * 32;
        *(uint4v*)(d0) = r8[0]; *(uint4v*)(d0 + 8) = r8[1];
        *(uint4v*)(d0 + 16) = r8[2]; *(uint4v*)(d0 + 24) = r8[3];
        *(uint4v*)(d1) = r8[4]; *(uint4v*)(d1 + 8) = r8[5];
        *(uint4v*)(d1 + 16) = r8[6]; *(uint4v*)(d1 + 24) = r8[7];
      } else {                        // v -> vT[img][pix][32] bf16
        u16* d0 = outT2 + ((size_t)(bb * NHEADS + h0) * PIX + pp) * 32;
        u16* d1 = outT2 + ((size_t)(bb * NHEADS + h0 + 1) * PIX + pp) * 32;
        *(uint4v*)(d0) = r8[0]; *(uint4v*)(d0 + 8) = r8[1];
        *(uint4v*)(d0 + 16) = r8[2]; *(uint4v*)(d0 + 24) = r8[3];
        *(uint4v*)(d1) = r8[4]; *(uint4v*)(d1 + 8) = r8[5];
        *(uint4v*)(d1 + 16) = r8[6]; *(uint4v*)(d1 + 24) = r8[7];
      }
    } else if (EPI == MG_PROJ) {
      u16* d = outT + (size_t)gp * CDIM + o0;
#pragma unroll
      for (int g = 0; g < 4 * MT; g++) *(uint4v*)(d + g * 8) = r8[g];
    } else {  // GELU -> hT [gp][768]
      u16* d = outT + (size_t)gp * 768 + o0;
#pragma unroll
      for (int g = 0; g < 4 * MT; g++) *(uint4v*)(d + g * 8) = r8[g];
    }
  }
}

// ------ 7x7 attn conv (FP8, ping-pong pair-batched MLP) + fused softmax/PV --
#define APL 1576   // fp8 patch plane stride (bytes)
#define VPS 40
#define SMS 65
#define DIV7(t) (((t) * 9363) >> 16)
#define LPOF(t) ((t) + 7 * DIV7(t))

__global__ __launch_bounds__(256, 4) void attn_fused_k(
    const u16* __restrict__ qkT, const u8* __restrict__ wTb8,
    const u16* __restrict__ vT,
    const float* __restrict__ dm_b, const float* __restrict__ rel_bias,
    u16* __restrict__ attnoT) {
  __shared__ __align__(16) u16 shraw[14216];   // 28432 B
  u8* patchB = (u8*)shraw;                     // phase1: 8 x 1576B = 12.6 KB
  int img = blockIdx.x / 49;
  int tile = blockIdx.x % 49;
  int y0 = (tile / 7) * 8, x0 = (tile % 7) * 8;
  int tid = threadIdx.x;
  const u16* qbase = qkT + (size_t)img * PIX * 64;
  for (int idx = tid; idx < 1568; idx += 256) {
    int lp = idx >> 3, g = idx & 7;
    int r = lp / 14, c = lp - r * 14;
    int gy = y0 - 3 + r, gx = x0 - 3 + c;
    uint2v out8 = {0u, 0u};
    if ((unsigned)gy < 56u && (unsigned)gx < 56u) {
      uint4v v = *(const uint4v*)(qbase + (size_t)(gy * 56 + gx) * 64 + g * 8);
      const u16* h = (const u16*)&v;
      float f[8];
#pragma unroll
      for (int e = 0; e < 8; e++) {
        unsigned u = ((unsigned)h[e]) << 16;
        f[e] = __builtin_bit_cast(float, u);
      }
      int lo = __builtin_amdgcn_cvt_pk_fp8_f32(f[0], f[1], 0, false);
      lo = __builtin_amdgcn_cvt_pk_fp8_f32(f[2], f[3], lo, true);
      int hi2 = __builtin_amdgcn_cvt_pk_fp8_f32(f[4], f[5], 0, false);
      hi2 = __builtin_amdgcn_cvt_pk_fp8_f32(f[6], f[7], hi2, true);
      out8[0] = lo; out8[1] = hi2;
    }
    *(uint2v*)&patchB[g * APL + lp * 8] = out8;
  }
  __syncthreads();

  int lane = tid & 63, wid = tid >> 6;
  int Mtile = wid & 1, Ntile = wid >> 1;
  int n = lane & 31, kgrp = lane >> 5;
  int py = Ntile * 4 + (n >> 3), px = n & 7;
  int lpb = py * 14 + px;
  f32x16 acc0, acc1;
#pragma unroll
  for (int i = 0; i < 16; i++) { acc0[i] = 0.f; acc1[i] = 0.f; }

  const u8* Ab = wTb8 + (size_t)Mtile * 100352 + lane * 8;
  uint2v A0[8], A1[8], B0[8];

  // LOADA: fetch the 8 A-frags (2 taps x 4 ch) of pair PR (clamped) into BUF
#define LOADA(BUF, PR) { \
  _Pragma("unroll") \
  for (int c4 = 0; c4 < 8; c4++) { \
    int t_ = (PR) * 2 + (c4 >> 2); if (t_ > 48) t_ = 48; \
    BUF[c4] = *(const uint2v*)(Ab + t_ * 2048 + (c4 & 3) * 512); } }

  // STEPB: batch the 8 B ds_reads of pair PR, then 8 MFMAs on BUF
#define STEPB(BUF, PR) { \
  _Pragma("unroll") \
  for (int c4 = 0; c4 < 8; c4++) { \
    int t_ = (PR) * 2 + (c4 >> 2); \
    int lp_ = lpb + LPOF(t_); \
    B0[c4] = *(const uint2v*)&patchB[((c4 & 3) * 2 + kgrp) * APL + lp_ * 8]; } \
  _Pragma("unroll") \
  for (int c4 = 0; c4 < 8; c4++) { \
    if (c4 & 1) \
      acc1 = __builtin_amdgcn_mfma_f32_32x32x16_fp8_fp8( \
          __builtin_bit_cast(long, BUF[c4]), __builtin_bit_cast(long, B0[c4]), acc1, 0, 0, 0); \
    else \
      acc0 = __builtin_amdgcn_mfma_f32_32x32x16_fp8_fp8( \
          __builtin_bit_cast(long, BUF[c4]), __builtin_bit_cast(long, B0[c4]), acc0, 0, 0, 0); } }

  LOADA(A0, 0);
#pragma unroll
  for (int th = 0; th < 12; th++) {
    LOADA(A1, 2 * th + 1);        // prefetch next pair while computing current
    STEPB(A0, 2 * th);
    LOADA(A0, 2 * th + 2);
    STEPB(A1, 2 * th + 1);
  }
  // tail: tap 48 (A0[0..3] hold pair-24 = tap 48, ch 0..3)
  {
    int lp_ = lpb + LPOF(48);
#pragma unroll
    for (int c4 = 0; c4 < 4; c4++) {
      uint2v b = *(const uint2v*)&patchB[(c4 * 2 + kgrp) * APL + lp_ * 8];
      if (c4 & 1)
        acc1 = __builtin_amdgcn_mfma_f32_32x32x16_fp8_fp8(
            __builtin_bit_cast(long, A0[c4]), __builtin_bit_cast(long, b), acc1, 0, 0, 0);
      else
        acc0 = __builtin_amdgcn_mfma_f32_32x32x16_fp8_fp8(
            __builtin_bit_cast(long, A0[c4]), __builtin_bit_cast(long, b), acc0, 0, 0, 0);
    }
  }

  // ---- fused tail: logits -> smx[49][SMS], v-patch -> vp, softmax, PV ------
  __syncthreads();
  float* smx = (float*)shraw;            // 49 x 65 x 4 = 12740 B
  u16* vp = shraw + 6376;                // [196 pix][VPS] bf16 (15680 B)
  int head = img % NHEADS;
#pragma unroll
  for (int r = 0; r < 16; r++) {
    int ko = Mtile * 32 + (r & 3) + 8 * (r >> 2) + 4 * kgrp;
    if (ko < KWIN)
      smx[ko * SMS + Ntile * 32 + n] =
          acc0[r] + acc1[r] + dm_b[ko] + rel_bias[ko * NHEADS + head];
  }
  const u16* vbase = vT + (size_t)img * PIX * 32;
  for (int idx = tid; idx < 784; idx += 256) {
    int g = idx & 3, lp = idx >> 2;
    int r = lp / 14, c = lp - r * 14;
    int gy = y0 - 3 + r, gx = x0 - 3 + c;
    uint4v val = {0u, 0u, 0u, 0u};
    if ((unsigned)gy < 56u && (unsigned)gx < 56u)
      val = *(const uint4v*)(vbase + (size_t)(gy * 56 + gx) * 32 + g * 8);
    *(uint4v*)&vp[lp * VPS + g * 8] = val;
  }
  __syncthreads();
  {
    int pxs = tid >> 2, q4 = tid & 3;
    int k0 = q4 * 13;
    int k1 = (q4 == 3) ? KWIN : k0 + 13;
    float m = -1e30f;
    for (int k = k0; k < k1; k++) m = fmaxf(m, smx[k * SMS + pxs]);
    m = fmaxf(m, __shfl_xor(m, 1, 64));
    m = fmaxf(m, __shfl_xor(m, 2, 64));
    float ssum = 0.f;
    for (int k = k0; k < k1; k++) {
      float e = __expf(smx[k * SMS + pxs] - m);
      smx[k * SMS + pxs] = e;
      ssum += e;
    }
    ssum += __shfl_xor(ssum, 1, 64);
    ssum += __shfl_xor(ssum, 2, 64);
    float inv = 1.f / ssum;
    for (int k = k0; k < k1; k++) smx[k * SMS + pxs] *= inv;
  }
  __syncthreads();
  int pxl = tid & 63, co = tid >> 6;
  int pyy = pxl >> 3, pxx = pxl & 7;
  float o8[8] = {0.f, 0.f, 0.f, 0.f, 0.f, 0.f, 0.f, 0.f};
#pragma unroll
  for (int kh = 0; kh < 7; kh++) {
#pragma unroll
    for (int kw = 0; kw < 7; kw++) {
      float p = smx[(kh * 7 + kw) * SMS + pxl];
      bf16x8 v = *(const bf16x8*)&vp[((pyy + kh) * 14 + pxx + kw) * VPS + co * 8];
#pragma unroll
      for (int j = 0; j < 8; j++) o8[j] += p * (float)v[j];
    }
  }
  int gp = (y0 + pyy) * 56 + x0 + pxx;
  int b = img / NHEADS;
  __hip_bfloat16 ob[8];
#pragma unroll
  for (int j = 0; j < 8; j++) ob[j] = __float2bfloat16(o8[j]);
  *(uint4v*)(attnoT + ((size_t)b * PIX + gp) * CDIM + head * 32 + co * 8) = *(uint4v*)ob;
}

// ---------------- launch ----------------------------------------------------
extern "C" void kernel_launch(void* const* d_in, const int* in_sizes, int n_in,
                              void* d_out, int out_size, void* d_ws, size_t ws_size,
                              hipStream_t stream) {
  const float* x        = (const float*)d_in[0];
  const float* bn_gamma = (const float*)d_in[1];
  const float* bn_beta  = (const float*)d_in[2];
  const float* qkv_w    = (const float*)d_in[3];
  const float* qkv_b    = (const float*)d_in[4];
  const float* dm_w     = (const float*)d_in[5];
  const float* dm_b     = (const float*)d_in[6];
  const float* rel_bias = (const float*)d_in[7];
  const float* proj_w   = (const float*)d_in[8];
  const float* proj_b   = (const float*)d_in[9];
  const float* c1_w     = (const float*)d_in[10];
  const float* c1_b     = (const float*)d_in[11];
  const float* c2_w     = (const float*)d_in[12];
  const float* c2_b     = (const float*)d_in[13];
  float* out = (float*)d_out;
  float* ws  = (float*)d_ws;

  float* stats   = ws;                          // 384 f
  float* b_eff   = stats + 384;                 // 576 f
  u16*   pk_qkv  = (u16*)(b_eff + 576);         // 110592 u16
  u16*   pk_proj = pk_qkv + 110592;             // 36864
  u16*   pk_c1   = pk_proj + 36864;             // 147456
  u16*   pk_c2   = pk_c1 + 147456;              // 147456
  u8*    wTb8    = (u8*)(pk_c2 + 147456);       // 200704 bytes (fp8)
  u16*   xsp     = (u16*)(wTb8 + 200704);       // spare region
  u16*   qkT     = xsp + 2408448;               // 4816896 u16
  u16*   vT      = qkT + 4816896;               // 2408448 u16
  u16*   attnoT  = vT + 2408448;                // 2408448 u16
  float* x1      = (float*)(attnoT + 2408448);  // 2408448 f
  u16*   x1T     = (u16*)(x1 + 2408448);        // 2408448 u16
  u16*   hT      = xsp;  // alias over dead xsp+qkT+vT

  bn_stats_k<<<CDIM, 256, 0, stream>>>(x, stats);
  prep3_k<<<946, 256, 0, stream>>>(dm_w, wTb8, proj_w, pk_proj, c1_w, pk_c1,
                                   c2_w, pk_c2);
  fold_pack_k<<<576, 192, 0, stream>>>(qkv_w, qkv_b, bn_gamma, bn_beta, stats,
                                       pk_qkv, b_eff);

  mgemm_k<MG_QKV, 2><<<dim3(49, 9), 256, 0, stream>>>(
      nullptr, pk_qkv, b_eff, nullptr, qkT, vT, x, 192);
  attn_fused_k<<<NIMG * 49, 256, 0, stream>>>(qkT, wTb8, vT, dm_b, rel_bias, attnoT);
  mgemm_k<MG_PROJ, 1><<<dim3(49, 6), 256, 0, stream>>>(
      attnoT, pk_proj, proj_b, x1, x1T, nullptr, x, 192);
  mgemm_k<MG_GELU, 2><<<dim3(49, 12), 256, 0, stream>>>(
      x1T, pk_c1, c1_b, nullptr, hT, nullptr, nullptr, 192);
  mgemm_k<MG_C2, 1><<<dim3(49, 6), 256, 0, stream>>>(
      hT, pk_c2, c2_b, out, nullptr, nullptr, x1, 768);
}

// Round 14
// 135.509 us; speedup vs baseline: 1.1178x; 1.1178x over previous
//
#include <hip/hip_runtime.h>
#include <hip/hip_bf16.h>
#include <math.h>

#define CDIM 192
#define NHEADS 6
#define WIN 7
#define KWIN 49
#define BATCH 4
#define PIX 3136      // 56*56
#define NPIX 12544    // BATCH*PIX
#define NIMG 24       // BATCH*NHEADS
#define EPSV 1e-5f

typedef __bf16 bf16x8 __attribute__((ext_vector_type(8)));
typedef float f32x16 __attribute__((ext_vector_type(16)));
typedef unsigned int uint4v __attribute__((ext_vector_type(4)));
typedef unsigned int uint2v __attribute__((ext_vector_type(2)));
typedef int int4x __attribute__((ext_vector_type(4)));
typedef int int8x __attribute__((ext_vector_type(8)));
typedef unsigned short u16;
typedef unsigned char u8;

__device__ inline u8 f32_to_fp8(float v) {
  return (u8)(__builtin_amdgcn_cvt_pk_fp8_f32(v, 0.f, 0, false) & 0xFF);
}

// 8 bf16 (as uint4v) -> 8 fp8 bytes (uint2v)
__device__ inline uint2v bf8_to_fp8x8(uint4v v) {
  const u16* h = (const u16*)&v;
  float f[8];
#pragma unroll
  for (int e = 0; e < 8; e++) {
    unsigned u = ((unsigned)h[e]) << 16;
    f[e] = __builtin_bit_cast(float, u);
  }
  int lo = __builtin_amdgcn_cvt_pk_fp8_f32(f[0], f[1], 0, false);
  lo = __builtin_amdgcn_cvt_pk_fp8_f32(f[2], f[3], lo, true);
  int hi = __builtin_amdgcn_cvt_pk_fp8_f32(f[4], f[5], 0, false);
  hi = __builtin_amdgcn_cvt_pk_fp8_f32(f[6], f[7], hi, true);
  uint2v r = {(unsigned)lo, (unsigned)hi};
  return r;
}

// ---------------- BN stats ---------------------------------------------------
__global__ __launch_bounds__(256) void bn_stats_k(const float* __restrict__ x,
                                                  float* __restrict__ stats) {
  int c = blockIdx.x;
  float s = 0.f, q = 0.f;
  for (int n = threadIdx.x; n < BATCH * PIX; n += 256) {
    int b = n / PIX, p = n - b * PIX;
    float v = x[((size_t)b * CDIM + c) * PIX + p];
    s += v; q += v * v;
  }
  __shared__ float rs[256], rq[256];
  rs[threadIdx.x] = s; rq[threadIdx.x] = q;
  __syncthreads();
  for (int st = 128; st > 0; st >>= 1) {
    if (threadIdx.x < st) { rs[threadIdx.x] += rs[threadIdx.x + st]; rq[threadIdx.x] += rq[threadIdx.x + st]; }
    __syncthreads();
  }
  if (threadIdx.x == 0) {
    float mean = rs[0] / (float)(BATCH * PIX);
    float var = rq[0] / (float)(BATCH * PIX) - mean * mean;
    stats[c] = mean;
    stats[CDIM + c] = rsqrtf(var + EPSV);
  }
}

// ------- fold BN + q-scale into qkv weights, writing PACKED frags directly --
__global__ __launch_bounds__(192) void fold_pack_k(
    const float* __restrict__ qkv_w, const float* __restrict__ qkv_b,
    const float* __restrict__ gamma, const float* __restrict__ beta,
    const float* __restrict__ stats, u16* __restrict__ pk_qkv,
    float* __restrict__ b_eff) {
  int o = blockIdx.x, c = threadIdx.x;
  float alpha = gamma[c] * stats[CDIM + c];
  float shift = beta[c] - stats[c] * alpha;
  float w = qkv_w[o * CDIM + c];
  float scale = (o < CDIM) ? 0.17677669529663687f : 1.f;
  int t8 = ((((o >> 5) * 12 + (c >> 4)) * 64 + (((c >> 3) & 1) * 32 + (o & 31))) << 3) + (c & 7);
  ((__hip_bfloat16*)pk_qkv)[t8] = __float2bfloat16(w * alpha * scale);
  __shared__ float r[CDIM];
  r[c] = w * shift;
  __syncthreads();
  if (c == 0) {
    float s = 0.f;
    for (int i = 0; i < CDIM; i++) s += r[i];
    b_eff[o] = (qkv_b[o] + s) * scale;
  }
}

// ---------------- generic pack helper: W[Cout][Cin] -> frag-major -----------
__device__ inline void pack_one(const float* __restrict__ W, u16* __restrict__ out,
                                int Cin, int t) {
  int lane = t & 63, rest = t >> 6;
  int nK = Cin >> 4;
  int kk = rest % nK, mtg = rest / nK;
  int o = mtg * 32 + (lane & 31), c = kk * 16 + (lane >> 5) * 8;
  const float* src = W + (size_t)o * Cin + c;
  __hip_bfloat16 tmp[8];
#pragma unroll
  for (int e = 0; e < 8; e++) tmp[e] = __float2bfloat16(src[e]);
  *(uint4v*)(out + (size_t)t * 8) = *(uint4v*)tmp;
}

// --- merged prep: dm_w K=64-frag FP8 pack + proj/c1/c2 packs ----------------
// wTs8 layout: [tap][Mt][lane][e(32)]; ko = Mt*32+(lane&31), ci = (lane>>5)*32+e
__global__ __launch_bounds__(256) void prep3_k(
    const float* __restrict__ dm_w, u8* __restrict__ wTs8,
    const float* __restrict__ proj_w, u16* __restrict__ pk_proj,
    const float* __restrict__ c1_w, u16* __restrict__ pk_c1,
    const float* __restrict__ c2_w, u16* __restrict__ pk_c2) {
  int bid = blockIdx.x, tid = threadIdx.x;
  if (bid < 784) {
    int idx = bid * 256 + tid;          // < 200704
    int e = idx & 31;
    int tmp = idx >> 5;
    int lane = tmp & 63; tmp >>= 6;
    int Mt = tmp & 1;
    int tap = tmp >> 1;                 // 0..48
    int ko = Mt * 32 + (lane & 31);
    int ci = (lane >> 5) * 32 + e;
    float v = (ko < KWIN) ? dm_w[(size_t)ko * 3136 + ci * 49 + tap] : 0.f;
    wTs8[idx] = f32_to_fp8(v);
  } else if (bid < 802) {
    int t = (bid - 784) * 256 + tid;
    if (t < 4608) pack_one(proj_w, pk_proj, 192, t);
  } else if (bid < 874) {
    int t = (bid - 802) * 256 + tid;
    if (t < 18432) pack_one(c1_w, pk_c1, 192, t);
  } else {
    int t = (bid - 874) * 256 + tid;
    if (t < 18432) pack_one(c2_w, pk_c2, 768, t);
  }
}

// ---------------- MFMA GEMM (256px tile + A staged in LDS) ------------------
#define MG_QKV 0
#define MG_PROJ 1
#define MG_GELU 2
#define MG_C2 3
#define MGS 2056

template <int EPI>
__global__ __launch_bounds__(256, 3) void mgemm_k(
    const u16* __restrict__ Bm, const u16* __restrict__ Apk,
    const float* __restrict__ bias,
    float* __restrict__ outF, u16* __restrict__ outT, u16* __restrict__ outT2,
    u8* __restrict__ outQK8,
    const float* __restrict__ extra, int Cin) {
  __shared__ __align__(16) u16 Bs[8 * MGS];  // 32.9 KB
  __shared__ __align__(16) u16 As[4096];     // 8 KB
  int tid = threadIdx.x;
  int lane = tid & 63, wid = tid >> 6;
  int hi = lane >> 5, ln31 = lane & 31;
  int p0 = blockIdx.x * 256;
  int o0 = blockIdx.y * 64;
  int nK = Cin >> 4;
  f32x16 acc[2][2];
#pragma unroll
  for (int mt = 0; mt < 2; mt++)
#pragma unroll
    for (int nt = 0; nt < 2; nt++)
#pragma unroll
      for (int i = 0; i < 16; i++) acc[mt][nt][i] = 0.f;

  unsigned gp_s = p0 + tid;
  unsigned bb_s = gp_s / PIX, pp_s = gp_s - bb_s * PIX;

  for (int cc = 0; cc < Cin; cc += 64) {
    if (EPI == MG_QKV) {
#pragma unroll
      for (int g = 0; g < 8; g++) {
        const float* xb = extra + ((size_t)bb_s * CDIM + cc + g * 8) * PIX + pp_s;
        __hip_bfloat16 tmp[8];
#pragma unroll
        for (int e = 0; e < 8; e++) tmp[e] = __float2bfloat16(xb[(size_t)e * PIX]);
        *(uint4v*)&Bs[g * MGS + tid * 8] = *(uint4v*)tmp;
      }
    } else {
#pragma unroll
      for (int i = 0; i < 8; i++) {
        int idx = i * 256 + tid;
        int g = idx & 7, p = idx >> 3;
        uint4v v = *(const uint4v*)(Bm + (size_t)(p0 + p) * Cin + cc + g * 8);
        *(uint4v*)&Bs[g * MGS + p * 8] = v;
      }
    }
#pragma unroll
    for (int i = 0; i < 2; i++) {
      int idx = i * 256 + tid;
      int frag = idx >> 6, l64 = idx & 63;
      int mt = frag >> 2, ks = frag & 3;
      uint4v v = *(const uint4v*)(Apk +
          (size_t)(((o0 >> 5) + mt) * nK + (cc >> 4) + ks) * 512 + l64 * 8);
      *(uint4v*)&As[frag * 512 + l64 * 8] = v;
    }
    __syncthreads();
    int pA = wid * 64 + ln31;
    int pB = pA + 32;
#pragma unroll
    for (int ks = 0; ks < 4; ks++) {
      int g = ks * 2 + hi;
      bf16x8 b0 = *(const bf16x8*)&Bs[g * MGS + pA * 8];
      bf16x8 b1 = *(const bf16x8*)&Bs[g * MGS + pB * 8];
      bf16x8 a0 = *(const bf16x8*)&As[ks * 512 + lane * 8];
      bf16x8 a1 = *(const bf16x8*)&As[(4 + ks) * 512 + lane * 8];
      acc[0][0] = __builtin_amdgcn_mfma_f32_32x32x16_bf16(a0, b0, acc[0][0], 0, 0, 0);
      acc[0][1] = __builtin_amdgcn_mfma_f32_32x32x16_bf16(a0, b1, acc[0][1], 0, 0, 0);
      acc[1][0] = __builtin_amdgcn_mfma_f32_32x32x16_bf16(a1, b0, acc[1][0], 0, 0, 0);
      acc[1][1] = __builtin_amdgcn_mfma_f32_32x32x16_bf16(a1, b1, acc[1][1], 0, 0, 0);
    }
    __syncthreads();
  }

  // ---- epilogue ----
  if (EPI == MG_C2) {
#pragma unroll
    for (int mt = 0; mt < 2; mt++)
#pragma unroll
      for (int r = 0; r < 16; r++) {
        int o = o0 + mt * 32 + (r & 3) + 8 * (r >> 2) + 4 * hi;
        float bv = bias[o];
#pragma unroll
        for (int nt = 0; nt < 2; nt++) {
          unsigned gp = p0 + wid * 64 + nt * 32 + ln31;
          unsigned bb = gp / PIX, pp = gp - bb * PIX;
          size_t oi = ((size_t)bb * CDIM + o) * PIX + pp;
          outF[oi] = acc[mt][nt][r] + bv + extra[oi];
        }
      }
  } else {
#pragma unroll
    for (int mt = 0; mt < 2; mt++)
#pragma unroll
      for (int r = 0; r < 16; r++) {
        int o_loc = mt * 32 + (r & 3) + 8 * (r >> 2) + 4 * hi;
        int o = o0 + o_loc;
        float bv = bias[o];
#pragma unroll
        for (int nt = 0; nt < 2; nt++) {
          int p_loc = wid * 64 + nt * 32 + ln31;
          float val = acc[mt][nt][r] + bv;
          if (EPI == MG_PROJ) {
            unsigned gp = p0 + p_loc;
            unsigned bb = gp / PIX, pp = gp - bb * PIX;
            size_t oi = ((size_t)bb * CDIM + o) * PIX + pp;
            val += extra[oi];
            outF[oi] = val;
          }
          if (EPI == MG_GELU)
            val = 0.5f * val * (1.f + erff(val * 0.70710678118654752f));
          *(__hip_bfloat16*)&Bs[p_loc * 64 + (((o_loc >> 3) ^ (p_loc & 7)) << 3) + (o_loc & 7)] =
              __float2bfloat16(val);
        }
      }
    __syncthreads();
    int prow = wid * 64 + lane;
    int psw = prow & 7;
    uint4v r8[8];
#pragma unroll
    for (int g = 0; g < 8; g++)
      r8[g] = *(const uint4v*)&Bs[prow * 64 + ((g ^ psw) << 3)];
    unsigned gp = p0 + prow;
    if (EPI == MG_QKV) {
      unsigned bb = gp / PIX, pp = gp - bb * PIX;
      int s = o0 / 192;               // 0=q, 1=k, 2=v
      int rr = o0 - s * 192;
      int h0 = rr >> 5;
      if (s < 2) {
        // q,k -> fp8 qk8[img][pix][64]; head h gets bytes [s*32, s*32+32)
        uint2v c0 = bf8_to_fp8x8(r8[0]), c1 = bf8_to_fp8x8(r8[1]);
        uint2v c2 = bf8_to_fp8x8(r8[2]), c3 = bf8_to_fp8x8(r8[3]);
        uint2v c4 = bf8_to_fp8x8(r8[4]), c5 = bf8_to_fp8x8(r8[5]);
        uint2v c6 = bf8_to_fp8x8(r8[6]), c7 = bf8_to_fp8x8(r8[7]);
        uint4v w0 = {c0[0], c0[1], c1[0], c1[1]};
        uint4v w1 = {c2[0], c2[1], c3[0], c3[1]};
        uint4v w2 = {c4[0], c4[1], c5[0], c5[1]};
        uint4v w3 = {c6[0], c6[1], c7[0], c7[1]};
        u8* d0 = outQK8 + ((size_t)(bb * NHEADS + h0) * PIX + pp) * 64 + s * 32;
        u8* d1 = outQK8 + ((size_t)(bb * NHEADS + h0 + 1) * PIX + pp) * 64 + s * 32;
        *(uint4v*)(d0) = w0; *(uint4v*)(d0 + 16) = w1;
        *(uint4v*)(d1) = w2; *(uint4v*)(d1 + 16) = w3;
      } else {                        // v -> vT[img][pix][32] bf16
        u16* d0 = outT2 + ((size_t)(bb * NHEADS + h0) * PIX + pp) * 32;
        u16* d1 = outT2 + ((size_t)(bb * NHEADS + h0 + 1) * PIX + pp) * 32;
        *(uint4v*)(d0) = r8[0]; *(uint4v*)(d0 + 8) = r8[1];
        *(uint4v*)(d0 + 16) = r8[2]; *(uint4v*)(d0 + 24) = r8[3];
        *(uint4v*)(d1) = r8[4]; *(uint4v*)(d1 + 8) = r8[5];
        *(uint4v*)(d1 + 16) = r8[6]; *(uint4v*)(d1 + 24) = r8[7];
      }
    } else if (EPI == MG_PROJ) {
      u16* d = outT + (size_t)gp * CDIM + o0;
#pragma unroll
      for (int g = 0; g < 8; g++) *(uint4v*)(d + g * 8) = r8[g];
    } else {  // GELU -> hT [gp][768]
      u16* d = outT + (size_t)gp * 768 + o0;
#pragma unroll
      for (int g = 0; g < 8; g++) *(uint4v*)(d + g * 8) = r8[g];
    }
  }
}

// ------ 7x7 attn conv (MX-scaled fp8 K=64 MFMA) + fused softmax/PV ----------
// Per (wave, tap): ONE mfma_scale_f32_32x32x64_f8f6f4 (scales = 1.0) +
// 2 ds_read_b128 (B) + 2 global b128 (A). Patch: [lp][64B] fp8 with 16B-slot
// swizzle slot^((lp>>1)&3). 49 MFMAs/wave (vs 196 in K=16 form).
#define VPS 40
#define SMS 65
#define DIV7(t) (((t) * 9363) >> 16)
#define LPOF(t) ((t) + 7 * DIV7(t))

__global__ __launch_bounds__(256, 4) void attn_fused_k(
    const u8* __restrict__ qk8, const u8* __restrict__ wTs8,
    const u16* __restrict__ vT,
    const float* __restrict__ dm_b, const float* __restrict__ rel_bias,
    u16* __restrict__ attnoT) {
  __shared__ __align__(16) u16 shraw[14216];   // 28432 B
  u8* patchB = (u8*)shraw;                     // phase1: 196 x 64B = 12.5 KB
  int img = blockIdx.x / 49;
  int tile = blockIdx.x % 49;
  int y0 = (tile / 7) * 8, x0 = (tile % 7) * 8;
  int tid = threadIdx.x;
  const u8* qimg = qk8 + (size_t)img * PIX * 64;
  for (int idx = tid; idx < 784; idx += 256) {
    int lp = idx >> 2, slot = idx & 3;
    int r = lp / 14, c = lp - r * 14;
    int gy = y0 - 3 + r, gx = x0 - 3 + c;
    uint4v val = {0u, 0u, 0u, 0u};
    if ((unsigned)gy < 56u && (unsigned)gx < 56u)
      val = *(const uint4v*)(qimg + (size_t)(gy * 56 + gx) * 64 + slot * 16);
    *(uint4v*)&patchB[lp * 64 + ((slot ^ ((lp >> 1) & 3)) << 4)] = val;
  }
  __syncthreads();

  int lane = tid & 63, wid = tid >> 6;
  int Mtile = wid & 1, Ntile = wid >> 1;
  int n = lane & 31, hi = lane >> 5;
  int py = Ntile * 4 + (n >> 3), px = n & 7;
  int lpb = py * 14 + px;
  f32x16 acc0, acc1;
#pragma unroll
  for (int i = 0; i < 16; i++) { acc0[i] = 0.f; acc1[i] = 0.f; }

  const u8* Aw = wTs8 + Mtile * 2048 + lane * 32;
#pragma unroll
  for (int tap = 0; tap < KWIN; tap++) {
    int lp_ = lpb + LPOF(tap);
    const int4x* ap = (const int4x*)(Aw + tap * 4096);
    int4x alo = ap[0], ahi = ap[1];
    int sw = (lp_ >> 1) & 3;
    int4x blo = *(const int4x*)&patchB[lp_ * 64 + (((2 * hi) ^ sw) << 4)];
    int4x bhi = *(const int4x*)&patchB[lp_ * 64 + (((2 * hi + 1) ^ sw) << 4)];
    int8x a = __builtin_shufflevector(alo, ahi, 0, 1, 2, 3, 4, 5, 6, 7);
    int8x b = __builtin_shufflevector(blo, bhi, 0, 1, 2, 3, 4, 5, 6, 7);
    if (tap & 1)
      acc1 = __builtin_amdgcn_mfma_scale_f32_32x32x64_f8f6f4(
          a, b, acc1, 0, 0, 0, 127, 0, 127);
    else
      acc0 = __builtin_amdgcn_mfma_scale_f32_32x32x64_f8f6f4(
          a, b, acc0, 0, 0, 0, 127, 0, 127);
  }

  // ---- fused tail: logits -> smx[49][SMS], v-patch -> vp, softmax, PV ------
  __syncthreads();
  float* smx = (float*)shraw;            // 49 x 65 x 4 = 12740 B
  u16* vp = shraw + 6376;                // [196 pix][VPS] bf16 (15680 B)
  int head = img % NHEADS;
#pragma unroll
  for (int r = 0; r < 16; r++) {
    int ko = Mtile * 32 + (r & 3) + 8 * (r >> 2) + 4 * hi;
    if (ko < KWIN)
      smx[ko * SMS + Ntile * 32 + n] =
          acc0[r] + acc1[r] + dm_b[ko] + rel_bias[ko * NHEADS + head];
  }
  const u16* vbase = vT + (size_t)img * PIX * 32;
  for (int idx = tid; idx < 784; idx += 256) {
    int g = idx & 3, lp = idx >> 2;
    int r = lp / 14, c = lp - r * 14;
    int gy = y0 - 3 + r, gx = x0 - 3 + c;
    uint4v val = {0u, 0u, 0u, 0u};
    if ((unsigned)gy < 56u && (unsigned)gx < 56u)
      val = *(const uint4v*)(vbase + (size_t)(gy * 56 + gx) * 32 + g * 8);
    *(uint4v*)&vp[lp * VPS + g * 8] = val;
  }
  __syncthreads();
  {
    int pxs = tid >> 2, q4 = tid & 3;
    int k0 = q4 * 13;
    int k1 = (q4 == 3) ? KWIN : k0 + 13;
    float m = -1e30f;
    for (int k = k0; k < k1; k++) m = fmaxf(m, smx[k * SMS + pxs]);
    m = fmaxf(m, __shfl_xor(m, 1, 64));
    m = fmaxf(m, __shfl_xor(m, 2, 64));
    float ssum = 0.f;
    for (int k = k0; k < k1; k++) {
      float e = __expf(smx[k * SMS + pxs] - m);
      smx[k * SMS + pxs] = e;
      ssum += e;
    }
    ssum += __shfl_xor(ssum, 1, 64);
    ssum += __shfl_xor(ssum, 2, 64);
    float inv = 1.f / ssum;
    for (int k = k0; k < k1; k++) smx[k * SMS + pxs] *= inv;
  }
  __syncthreads();
  int pxl = tid & 63, co = tid >> 6;
  int pyy = pxl >> 3, pxx = pxl & 7;
  float o8[8] = {0.f, 0.f, 0.f, 0.f, 0.f, 0.f, 0.f, 0.f};
#pragma unroll
  for (int kh = 0; kh < 7; kh++) {
#pragma unroll
    for (int kw = 0; kw < 7; kw++) {
      float p = smx[(kh * 7 + kw) * SMS + pxl];
      bf16x8 v = *(const bf16x8*)&vp[((pyy + kh) * 14 + pxx + kw) * VPS + co * 8];
#pragma unroll
      for (int j = 0; j < 8; j++) o8[j] += p * (float)v[j];
    }
  }
  int gp = (y0 + pyy) * 56 + x0 + pxx;
  int b = img / NHEADS;
  __hip_bfloat16 ob[8];
#pragma unroll
  for (int j = 0; j < 8; j++) ob[j] = __float2bfloat16(o8[j]);
  *(uint4v*)(attnoT + ((size_t)b * PIX + gp) * CDIM + head * 32 + co * 8) = *(uint4v*)ob;
}

// ---------------- launch ----------------------------------------------------
extern "C" void kernel_launch(void* const* d_in, const int* in_sizes, int n_in,
                              void* d_out, int out_size, void* d_ws, size_t ws_size,
                              hipStream_t stream) {
  const float* x        = (const float*)d_in[0];
  const float* bn_gamma = (const float*)d_in[1];
  const float* bn_beta  = (const float*)d_in[2];
  const float* qkv_w    = (const float*)d_in[3];
  const float* qkv_b    = (const float*)d_in[4];
  const float* dm_w     = (const float*)d_in[5];
  const float* dm_b     = (const float*)d_in[6];
  const float* rel_bias = (const float*)d_in[7];
  const float* proj_w   = (const float*)d_in[8];
  const float* proj_b   = (const float*)d_in[9];
  const float* c1_w     = (const float*)d_in[10];
  const float* c1_b     = (const float*)d_in[11];
  const float* c2_w     = (const float*)d_in[12];
  const float* c2_b     = (const float*)d_in[13];
  float* out = (float*)d_out;
  float* ws  = (float*)d_ws;

  float* stats   = ws;                          // 384 f
  float* b_eff   = stats + 384;                 // 576 f
  u16*   pk_qkv  = (u16*)(b_eff + 576);         // 110592 u16
  u16*   pk_proj = pk_qkv + 110592;             // 36864
  u16*   pk_c1   = pk_proj + 36864;             // 147456
  u16*   pk_c2   = pk_c1 + 147456;              // 147456
  u8*    wTs8    = (u8*)(pk_c2 + 147456);       // 200704 B (fp8 K=64 frags)
  u16*   spare   = (u16*)(wTs8 + 200704);       // 4816896 u16 (hT alias head)
  u8*    qk8     = (u8*)(spare + 4816896);      // 4816896 B fp8
  u16*   vT      = (u16*)(qk8 + 4816896);       // 2408448 u16
  u16*   attnoT  = vT + 2408448;                // 2408448 u16
  float* x1      = (float*)(attnoT + 2408448);  // 2408448 f
  u16*   x1T     = (u16*)(x1 + 2408448);        // 2408448 u16
  u16*   hT      = spare;  // 9633792 u16 over dead spare+qk8+vT

  bn_stats_k<<<CDIM, 256, 0, stream>>>(x, stats);
  prep3_k<<<946, 256, 0, stream>>>(dm_w, wTs8, proj_w, pk_proj, c1_w, pk_c1,
                                   c2_w, pk_c2);
  fold_pack_k<<<576, 192, 0, stream>>>(qkv_w, qkv_b, bn_gamma, bn_beta, stats,
                                       pk_qkv, b_eff);

  mgemm_k<MG_QKV><<<dim3(49, 9), 256, 0, stream>>>(
      nullptr, pk_qkv, b_eff, nullptr, nullptr, vT, qk8, x, 192);
  attn_fused_k<<<NIMG * 49, 256, 0, stream>>>(qk8, wTs8, vT, dm_b, rel_bias, attnoT);
  mgemm_k<MG_PROJ><<<dim3(49, 3), 256, 0, stream>>>(
      attnoT, pk_proj, proj_b, x1, x1T, nullptr, nullptr, x, 192);
  mgemm_k<MG_GELU><<<dim3(49, 12), 256, 0, stream>>>(
      x1T, pk_c1, c1_b, nullptr, hT, nullptr, nullptr, nullptr, 192);
  mgemm_k<MG_C2><<<dim3(49, 3), 256, 0, stream>>>(
      hT, pk_c2, c2_b, out, nullptr, nullptr, nullptr, x1, 768);
}